// Round 6
// baseline (217.576 us; speedup 1.0000x reference)
//
#include <hip/hip_runtime.h>
#include <hip/hip_fp16.h>

#define NN 50000
#define NE 1000000
#define D  64
#define ED 16
#define CAP 64
#define BN_EPS 1e-5f

struct alignas(16) SE8  { int   v[8];  };   // 4 {src,eid} pairs
struct alignas(16) F16v { float f[16]; };   // one edge_attr row

// =====================  x -> fp16 side copy  =====================
__global__ __launch_bounds__(256) void xhalf_kernel(
    const float* __restrict__ x, __half* __restrict__ xh)
{
    const int i = blockIdx.x * 256 + threadIdx.x;       // one float4 each
    if (i >= NN * D / 4) return;
    const float4 a = reinterpret_cast<const float4*>(x)[i];
    ushort4 h;
    h.x = __half_as_ushort(__float2half(a.x));
    h.y = __half_as_ushort(__float2half(a.y));
    h.z = __half_as_ushort(__float2half(a.z));
    h.w = __half_as_ushort(__float2half(a.w));
    reinterpret_cast<ushort4*>(xh)[i] = h;
}

// =====================  path A: binned scatter + gather  =====================

__global__ __launch_bounds__(256) void scatter_kernel(
    const int* __restrict__ ei32,
    int*       __restrict__ cursor,
    int2*      __restrict__ padded)
{
    const int e = blockIdx.x * 256 + threadIdx.x;
    const int hi = ei32[2 * (threadIdx.x & 63) + 1];
    const bool is64 = !__any(hi != 0);
    if (e >= NE) return;
    const int src = is64 ? ei32[2 * e]        : ei32[e];
    const int dst = is64 ? ei32[2 * (NE + e)] : ei32[NE + e];
    const int slot = atomicAdd(&cursor[dst], 1);
    if (slot < CAP) padded[(size_t)dst * CAP + slot] = make_int2(src, e);
}

// one wave per node; edge attrs + indices through the SCALAR pipe.
// XH: read x from the fp16 side copy (halved working set -> L2-resident).
template<bool XH>
__global__ __launch_bounds__(256) void gather_kernel(
    const int2*  __restrict__ padded,
    const int*   __restrict__ cursor,
    const float* __restrict__ x,
    const __half* __restrict__ xh,
    const float* __restrict__ ea,
    const float* __restrict__ W_edge,
    const float* __restrict__ b_edge,
    float*       __restrict__ agg,
    int n0, int n1)
{
    const int tid  = threadIdx.x;
    const int lane = tid & 63;
    const int n = __builtin_amdgcn_readfirstlane(n0 + blockIdx.x * 4 + (tid >> 6));
    if (n >= n1) return;

    float wv[ED];
    #pragma unroll
    for (int i = 0; i < ED / 4; ++i) {
        float4 t = reinterpret_cast<const float4*>(W_edge)[lane * (ED / 4) + i];
        wv[4*i+0] = t.x; wv[4*i+1] = t.y; wv[4*i+2] = t.z; wv[4*i+3] = t.w;
    }
    const float bo = b_edge[lane];

    const int deg = __builtin_amdgcn_readfirstlane(min(cursor[n], CAP));
    const int2* row = padded + (size_t)n * CAP;

    float acc = 0.f;
    for (int e0 = 0; e0 < deg; e0 += 4) {
        const SE8 g = *reinterpret_cast<const SE8*>(row + e0);

        const bool l1 = (e0 + 1 < deg), l2 = (e0 + 2 < deg), l3 = (e0 + 3 < deg);
        const int src0 = __builtin_amdgcn_readfirstlane(g.v[0]);
        const int eid0 = __builtin_amdgcn_readfirstlane(g.v[1]);
        const int src1 = __builtin_amdgcn_readfirstlane(l1 ? g.v[2] : g.v[0]);
        const int eid1 = __builtin_amdgcn_readfirstlane(l1 ? g.v[3] : g.v[1]);
        const int src2 = __builtin_amdgcn_readfirstlane(l2 ? g.v[4] : g.v[0]);
        const int eid2 = __builtin_amdgcn_readfirstlane(l2 ? g.v[5] : g.v[1]);
        const int src3 = __builtin_amdgcn_readfirstlane(l3 ? g.v[6] : g.v[0]);
        const int eid3 = __builtin_amdgcn_readfirstlane(l3 ? g.v[7] : g.v[1]);

        const F16v a0 = *reinterpret_cast<const F16v*>(ea + (size_t)eid0 * ED);
        const F16v a1 = *reinterpret_cast<const F16v*>(ea + (size_t)eid1 * ED);
        const F16v a2 = *reinterpret_cast<const F16v*>(ea + (size_t)eid2 * ED);
        const F16v a3 = *reinterpret_cast<const F16v*>(ea + (size_t)eid3 * ED);

        float xv0, xv1, xv2, xv3;
        if (XH) {
            xv0 = __half2float(xh[(size_t)src0 * D + lane]);
            xv1 = __half2float(xh[(size_t)src1 * D + lane]);
            xv2 = __half2float(xh[(size_t)src2 * D + lane]);
            xv3 = __half2float(xh[(size_t)src3 * D + lane]);
        } else {
            xv0 = x[(size_t)src0 * D + lane];
            xv1 = x[(size_t)src1 * D + lane];
            xv2 = x[(size_t)src2 * D + lane];
            xv3 = x[(size_t)src3 * D + lane];
        }

        const float m1 = l1 ? 1.f : 0.f;
        const float m2 = l2 ? 1.f : 0.f;
        const float m3 = l3 ? 1.f : 0.f;

        float d0 = bo, d1 = bo, d2 = bo, d3 = bo;
        #pragma unroll
        for (int k = 0; k < ED; ++k) {
            d0 += a0.f[k] * wv[k];
            d1 += a1.f[k] * wv[k];
            d2 += a2.f[k] * wv[k];
            d3 += a3.f[k] * wv[k];
        }
        acc += fmaxf(d0 + xv0, 0.f);
        acc += m1 * fmaxf(d1 + xv1, 0.f);
        acc += m2 * fmaxf(d2 + xv2, 0.f);
        acc += m3 * fmaxf(d3 + xv3, 0.f);
    }
    agg[(size_t)n * D + lane] = acc;
}

// =====================  path B fallback: atomic edge kernel  =================

__global__ __launch_bounds__(256) void edge_kernel(
    const float* __restrict__ x,
    const int*   __restrict__ ei32,
    const float* __restrict__ ea,
    const float* __restrict__ W_edge,
    const float* __restrict__ b_edge,
    float*       __restrict__ agg)
{
    __shared__ float s_ea[64 * ED];
    __shared__ int   s_src[64];
    __shared__ int   s_dst[64];

    const int tid  = threadIdx.x;
    const int lane = tid & 63;
    const int wave = tid >> 6;
    const long long ebase = (long long)blockIdx.x * 64;

    const int hi = ei32[2 * lane + 1];
    const bool is64 = !__any(hi != 0);

    float w[ED];
    #pragma unroll
    for (int i = 0; i < ED / 4; ++i) {
        float4 t = reinterpret_cast<const float4*>(W_edge)[lane * (ED / 4) + i];
        w[4*i+0] = t.x; w[4*i+1] = t.y; w[4*i+2] = t.z; w[4*i+3] = t.w;
    }
    const float bo = b_edge[lane];

    reinterpret_cast<float4*>(s_ea)[tid] =
        reinterpret_cast<const float4*>(ea + ebase * ED)[tid];

    if (tid < 64) {
        long long e = ebase + tid;
        s_src[tid] = is64 ? ei32[2 * e] : ei32[e];
    } else if (tid < 128) {
        long long e = ebase + (tid - 64);
        s_dst[tid - 64] = is64 ? ei32[2 * (NE + e)] : ei32[NE + e];
    }
    __syncthreads();

    #pragma unroll 4
    for (int i = 0; i < 16; ++i) {
        const int el = wave * 16 + i;
        float acc = bo;
        const float* er = s_ea + el * ED;
        #pragma unroll
        for (int k = 0; k < ED; ++k) acc += er[k] * w[k];
        const long long s = s_src[el];
        const long long d = s_dst[el];
        float m = fmaxf(acc + x[s * D + lane], 0.f);
        atomicAdd(&agg[d * D + lane], m);
    }
}

// =====================  node stages  =====================

__global__ __launch_bounds__(256) void node1_kernel(
    const float* __restrict__ x,
    const float* __restrict__ agg,
    const float* __restrict__ W1,
    const float* __restrict__ b1,
    float*       __restrict__ h1,
    float*       __restrict__ colsum,
    float*       __restrict__ colsumsq)
{
    __shared__ float s_h[64 * D];
    const int tid  = threadIdx.x;
    const int o    = tid & 63;
    const int wave = tid >> 6;
    const long long rbase = (long long)blockIdx.x * 64;

    float w[D];
    #pragma unroll
    for (int i = 0; i < D / 4; ++i) {
        float4 t = reinterpret_cast<const float4*>(W1)[o * (D / 4) + i];
        w[4*i+0] = t.x; w[4*i+1] = t.y; w[4*i+2] = t.z; w[4*i+3] = t.w;
    }

    #pragma unroll
    for (int i = 0; i < 4; ++i) {
        const int f4 = tid + 256 * i;
        const long long row = rbase + (f4 >> 4);
        float4 t = make_float4(0.f, 0.f, 0.f, 0.f);
        if (row < NN) {
            float4 a = reinterpret_cast<const float4*>(x)  [row * (D/4) + (f4 & 15)];
            float4 g = reinterpret_cast<const float4*>(agg)[row * (D/4) + (f4 & 15)];
            t.x = a.x + g.x; t.y = a.y + g.y; t.z = a.z + g.z; t.w = a.w + g.w;
        }
        reinterpret_cast<float4*>(s_h)[f4] = t;
    }
    __syncthreads();

    const float bb = b1[o];
    float psum = 0.f, psq = 0.f;
    for (int i = 0; i < 16; ++i) {
        const int r = wave + 4 * i;
        const long long row = rbase + r;
        float acc = bb;
        const float4* sr = reinterpret_cast<const float4*>(s_h + r * D);
        #pragma unroll
        for (int k = 0; k < D / 4; ++k) {
            float4 v = sr[k];
            acc += v.x * w[4*k+0] + v.y * w[4*k+1] + v.z * w[4*k+2] + v.w * w[4*k+3];
        }
        if (row < NN) {
            h1[row * D + o] = acc;
            psum += acc;
            psq  += acc * acc;
        }
    }
    __syncthreads();
    s_h[wave * 64 + o]       = psum;
    s_h[256 + wave * 64 + o] = psq;
    __syncthreads();
    if (tid < 64) {
        float s0 = s_h[tid] + s_h[64 + tid] + s_h[128 + tid] + s_h[192 + tid];
        float q0 = s_h[256 + tid] + s_h[320 + tid] + s_h[384 + tid] + s_h[448 + tid];
        atomicAdd(&colsum[tid], s0);
        atomicAdd(&colsumsq[tid], q0);
    }
}

__global__ void bnstats_kernel(
    const float* __restrict__ colsum,
    const float* __restrict__ colsumsq,
    const float* __restrict__ gamma,
    const float* __restrict__ beta,
    float*       __restrict__ scale,
    float*       __restrict__ shift)
{
    const int o = threadIdx.x;
    const float inv_n = 1.f / (float)NN;
    const float mean = colsum[o] * inv_n;
    const float var  = colsumsq[o] * inv_n - mean * mean;
    const float sc   = gamma[o] * rsqrtf(var + BN_EPS);
    scale[o] = sc;
    shift[o] = beta[o] - mean * sc;
}

__global__ __launch_bounds__(256) void node2_kernel(
    const float* __restrict__ h1,
    const float* __restrict__ scale,
    const float* __restrict__ shift,
    const float* __restrict__ W2,
    const float* __restrict__ b2,
    float*       __restrict__ out)
{
    __shared__ float s_a[64 * D];
    __shared__ float s_sc[D];
    __shared__ float s_sh[D];
    const int tid  = threadIdx.x;
    const int o    = tid & 63;
    const int wave = tid >> 6;
    const long long rbase = (long long)blockIdx.x * 64;

    if (tid < D) { s_sc[tid] = scale[tid]; s_sh[tid] = shift[tid]; }

    float w[D];
    #pragma unroll
    for (int i = 0; i < D / 4; ++i) {
        float4 t = reinterpret_cast<const float4*>(W2)[o * (D / 4) + i];
        w[4*i+0] = t.x; w[4*i+1] = t.y; w[4*i+2] = t.z; w[4*i+3] = t.w;
    }
    __syncthreads();

    #pragma unroll
    for (int i = 0; i < 4; ++i) {
        const int f4 = tid + 256 * i;
        const long long row = rbase + (f4 >> 4);
        float4 t = make_float4(0.f, 0.f, 0.f, 0.f);
        if (row < NN) {
            float4 v = reinterpret_cast<const float4*>(h1)[row * (D/4) + (f4 & 15)];
            const int c = (f4 & 15) * 4;
            t.x = fmaxf(v.x * s_sc[c+0] + s_sh[c+0], 0.f);
            t.y = fmaxf(v.y * s_sc[c+1] + s_sh[c+1], 0.f);
            t.z = fmaxf(v.z * s_sc[c+2] + s_sh[c+2], 0.f);
            t.w = fmaxf(v.w * s_sc[c+3] + s_sh[c+3], 0.f);
        }
        reinterpret_cast<float4*>(s_a)[f4] = t;
    }
    __syncthreads();

    const float bb = b2[o];
    for (int i = 0; i < 16; ++i) {
        const int r = wave + 4 * i;
        const long long row = rbase + r;
        float acc = bb;
        const float4* sr = reinterpret_cast<const float4*>(s_a + r * D);
        #pragma unroll
        for (int k = 0; k < D / 4; ++k) {
            float4 v = sr[k];
            acc += v.x * w[4*k+0] + v.y * w[4*k+1] + v.z * w[4*k+2] + v.w * w[4*k+3];
        }
        if (row < NN) out[row * D + o] = acc;
    }
}

// =====================  launch  =====================

extern "C" void kernel_launch(void* const* d_in, const int* in_sizes, int n_in,
                              void* d_out, int out_size, void* d_ws, size_t ws_size,
                              hipStream_t stream)
{
    const float* x      = (const float*)d_in[0];
    const int*   ei32   = (const int*)  d_in[1];
    const float* ea     = (const float*)d_in[2];
    const float* W_edge = (const float*)d_in[3];
    const float* b_edge = (const float*)d_in[4];
    const float* W1     = (const float*)d_in[5];
    const float* b1     = (const float*)d_in[6];
    const float* gamma  = (const float*)d_in[7];
    const float* beta   = (const float*)d_in[8];
    const float* W2     = (const float*)d_in[9];
    const float* b2     = (const float*)d_in[10];
    float* out = (float*)d_out;

    float*  agg      = (float*)d_ws;                      // NN*D floats
    float*  h1       = agg + (size_t)NN * D;              // NN*D floats
    int*    cursor   = (int*)(h1 + (size_t)NN * D);       // NN ints
    float*  colsum   = (float*)(cursor + NN);             // 64
    float*  colsumsq = colsum + 64;                       // 64
    float*  scale    = colsumsq + 64;                     // 64
    float*  shift    = scale + 64;                        // 64
    int2*   padded   = (int2*)(shift + 64);               // NN*CAP int2
    __half* xh       = (__half*)(padded + (size_t)NN * CAP); // NN*D halves

    const size_t need_base = (size_t)(2 * NN * D + NN + 256) * 4 + (size_t)NN * CAP * 8;
    const size_t need_xh   = need_base + (size_t)NN * D * 2;

    if (ws_size >= need_base) {
        hipMemsetAsync(cursor, 0, (size_t)(NN + 256) * 4, stream);
        scatter_kernel<<<(NE + 255) / 256, 256, 0, stream>>>(ei32, cursor, padded);
        if (ws_size >= need_xh) {
            xhalf_kernel<<<(NN * D / 4 + 255) / 256, 256, 0, stream>>>(x, xh);
            gather_kernel<true><<<NN / 8, 256, 0, stream>>>(padded, cursor, x, xh, ea, W_edge, b_edge, agg, 0, NN / 2);
            gather_kernel<true><<<NN / 8, 256, 0, stream>>>(padded, cursor, x, xh, ea, W_edge, b_edge, agg, NN / 2, NN);
        } else {
            gather_kernel<false><<<NN / 8, 256, 0, stream>>>(padded, cursor, x, xh, ea, W_edge, b_edge, agg, 0, NN / 2);
            gather_kernel<false><<<NN / 8, 256, 0, stream>>>(padded, cursor, x, xh, ea, W_edge, b_edge, agg, NN / 2, NN);
        }
    } else {
        hipMemsetAsync(agg, 0, (size_t)NN * D * 4, stream);
        hipMemsetAsync(cursor, 0, (size_t)(NN + 256) * 4, stream);
        edge_kernel<<<NE / 64, 256, 0, stream>>>(x, ei32, ea, W_edge, b_edge, agg);
    }
    node1_kernel<<<(NN + 63) / 64, 256, 0, stream>>>(x, agg, W1, b1, h1, colsum, colsumsq);
    bnstats_kernel<<<1, 64, 0, stream>>>(colsum, colsumsq, gamma, beta, scale, shift);
    node2_kernel<<<(NN + 63) / 64, 256, 0, stream>>>(h1, scale, shift, W2, b2, out);
}

// Round 8
// 172.330 us; speedup vs baseline: 1.2626x; 1.2626x over previous
//
#include <hip/hip_runtime.h>
#include <hip/hip_fp16.h>

#define NN 50000
#define NE 1000000
#define D  64
#define ED 16
#define CAP 64
#define BN_EPS 1e-5f
#define QSCALE 1048576.0f           // 2^20 fixed-point scale for deterministic agg

// radix partition params
#define BSH  8                      // 256 nodes per bucket
#define NBKT 196                    // ceil(50000/256)
#define BCAP 6144                   // per-bucket edge capacity (mean 5102, max ~5500)
#define EPB  4096                   // edges per pass-A block

struct alignas(16) SE8  { int   v[8];  };   // 4 {src,eid} pairs
struct alignas(16) F16v { float f[16]; };   // one edge_attr row

// =====================  x -> fp16 side copy  =====================
__global__ __launch_bounds__(256) void xhalf_kernel(
    const float* __restrict__ x, __half* __restrict__ xh)
{
    const int i = blockIdx.x * 256 + threadIdx.x;
    if (i >= NN * D / 4) return;
    const float4 a = reinterpret_cast<const float4*>(x)[i];
    ushort4 h;
    h.x = __half_as_ushort(__float2half(a.x));
    h.y = __half_as_ushort(__float2half(a.y));
    h.z = __half_as_ushort(__float2half(a.z));
    h.w = __half_as_ushort(__float2half(a.w));
    reinterpret_cast<ushort4*>(xh)[i] = h;
}

// ============ pass A: LDS radix partition of edges into 196 buckets ==========
__global__ __launch_bounds__(256) void partA_kernel(
    const int*  __restrict__ ei32,
    int*        __restrict__ gcur,      // [NBKT], zeroed
    uint2*      __restrict__ bucketed)  // [NBKT * BCAP]
{
    __shared__ uint2 s_staged[EPB];                       // 32 KB
    __shared__ int s_cnt[NBKT], s_pref[NBKT], s_cnt2[NBKT], s_gbase[NBKT];

    const int tid = threadIdx.x;
    const long long base = (long long)blockIdx.x * EPB;
    const int nedge = (int)((NE - base < EPB) ? (NE - base) : EPB);

    const int hi = ei32[2 * (tid & 63) + 1];
    const bool is64 = !__any(hi != 0);

    for (int i = tid; i < NBKT; i += 256) { s_cnt[i] = 0; s_cnt2[i] = 0; }
    __syncthreads();

    int srcv[16], dstv[16];
    #pragma unroll
    for (int i = 0; i < 16; ++i) {
        const int k = i * 256 + tid;
        int s = 0, d = 0;
        if (k < nedge) {
            const long long e = base + k;
            s = is64 ? ei32[2 * e]        : ei32[e];
            d = is64 ? ei32[2 * (NE + e)] : ei32[NE + e];
            atomicAdd(&s_cnt[d >> BSH], 1);
        }
        srcv[i] = s; dstv[i] = d;
    }
    __syncthreads();

    // inclusive Hillis-Steele scan over NBKT entries
    if (tid < NBKT) s_pref[tid] = s_cnt[tid];
    __syncthreads();
    for (int off = 1; off < NBKT; off <<= 1) {
        int v = 0;
        if (tid < NBKT && tid >= off) v = s_pref[tid - off];
        __syncthreads();
        if (tid < NBKT) s_pref[tid] += v;
        __syncthreads();
    }
    if (tid < NBKT) s_gbase[tid] = atomicAdd(&gcur[tid], s_cnt[tid]);
    __syncthreads();

    #pragma unroll
    for (int i = 0; i < 16; ++i) {
        const int k = i * 256 + tid;
        if (k < nedge) {
            const int d = dstv[i], b = d >> BSH;
            const int r = atomicAdd(&s_cnt2[b], 1);
            const int p = (s_pref[b] - s_cnt[b]) + r;     // excl prefix + rank
            s_staged[p] = make_uint2((unsigned)srcv[i] | ((unsigned)d << 16),
                                     (unsigned)(base + k));
        }
    }
    __syncthreads();

    for (int p = tid; p < nedge; p += 256) {
        const uint2 rec = s_staged[p];
        const int d = (int)(rec.x >> 16), b = d >> BSH;
        const int local = p - (s_pref[b] - s_cnt[b]);
        const int gpos = s_gbase[b] + local;
        if (gpos < BCAP)
            bucketed[(size_t)b * BCAP + gpos] = rec;
    }
}

// ===== pass B: per-bucket slot assignment (LDS cursors) + padded emit =======
__global__ __launch_bounds__(512) void partB_kernel(
    const uint2* __restrict__ bucketed,
    const int*   __restrict__ gcur,
    int*         __restrict__ cursor,   // [NN] out: degrees
    int2*        __restrict__ padded)
{
    __shared__ int s_deg[1 << BSH];
    const int tid = threadIdx.x;
    const int b = blockIdx.x;

    for (int i = tid; i < (1 << BSH); i += 512) s_deg[i] = 0;
    __syncthreads();

    const int cnt = min(gcur[b], BCAP);
    const uint2* reg = bucketed + (size_t)b * BCAP;
    for (int k = tid; k < cnt; k += 512) {
        const uint2 rec = reg[k];
        const int src = (int)(rec.x & 0xffffu);
        const int dst = (int)(rec.x >> 16);
        const int slot = atomicAdd(&s_deg[dst & ((1 << BSH) - 1)], 1);
        if (slot < CAP)
            padded[(size_t)dst * CAP + slot] = make_int2(src, (int)rec.y);
    }
    __syncthreads();
    for (int i = tid; i < (1 << BSH); i += 512) {
        const int n = (b << BSH) + i;
        if (n < NN) cursor[n] = s_deg[i];
    }
}

// ============== fallback scatter (global atomic slot assignment) =============
__global__ __launch_bounds__(256) void scatter_kernel(
    const int* __restrict__ ei32,
    int*       __restrict__ cursor,
    int2*      __restrict__ padded)
{
    const int e = blockIdx.x * 256 + threadIdx.x;
    const int hi = ei32[2 * (threadIdx.x & 63) + 1];
    const bool is64 = !__any(hi != 0);
    if (e >= NE) return;
    const int src = is64 ? ei32[2 * e]        : ei32[e];
    const int dst = is64 ? ei32[2 * (NE + e)] : ei32[NE + e];
    const int slot = atomicAdd(&cursor[dst], 1);
    if (slot < CAP) padded[(size_t)dst * CAP + slot] = make_int2(src, e);
}

// one wave per node; edge attrs + indices through the SCALAR pipe.
// Fixed-point (2^20) accumulation: integer add is exactly commutative, so
// the per-node sum is bitwise identical under ANY edge->slot permutation
// (atomic races in partA/partB/scatter can't perturb the output).
template<bool XH>
__global__ __launch_bounds__(256) void gather_kernel(
    const int2*  __restrict__ padded,
    const int*   __restrict__ cursor,
    const float* __restrict__ x,
    const __half* __restrict__ xh,
    const float* __restrict__ ea,
    const float* __restrict__ W_edge,
    const float* __restrict__ b_edge,
    float*       __restrict__ agg,
    int n0, int n1)
{
    const int tid  = threadIdx.x;
    const int lane = tid & 63;
    const int n = __builtin_amdgcn_readfirstlane(n0 + blockIdx.x * 4 + (tid >> 6));
    if (n >= n1) return;

    float wv[ED];
    #pragma unroll
    for (int i = 0; i < ED / 4; ++i) {
        float4 t = reinterpret_cast<const float4*>(W_edge)[lane * (ED / 4) + i];
        wv[4*i+0] = t.x; wv[4*i+1] = t.y; wv[4*i+2] = t.z; wv[4*i+3] = t.w;
    }
    const float bo = b_edge[lane];

    const int deg = __builtin_amdgcn_readfirstlane(min(cursor[n], CAP));
    const int2* row = padded + (size_t)n * CAP;

    int iacc = 0;
    for (int e0 = 0; e0 < deg; e0 += 4) {
        const SE8 g = *reinterpret_cast<const SE8*>(row + e0);

        const bool l1 = (e0 + 1 < deg), l2 = (e0 + 2 < deg), l3 = (e0 + 3 < deg);
        const int src0 = __builtin_amdgcn_readfirstlane(g.v[0]);
        const int eid0 = __builtin_amdgcn_readfirstlane(g.v[1]);
        const int src1 = __builtin_amdgcn_readfirstlane(l1 ? g.v[2] : g.v[0]);
        const int eid1 = __builtin_amdgcn_readfirstlane(l1 ? g.v[3] : g.v[1]);
        const int src2 = __builtin_amdgcn_readfirstlane(l2 ? g.v[4] : g.v[0]);
        const int eid2 = __builtin_amdgcn_readfirstlane(l2 ? g.v[5] : g.v[1]);
        const int src3 = __builtin_amdgcn_readfirstlane(l3 ? g.v[6] : g.v[0]);
        const int eid3 = __builtin_amdgcn_readfirstlane(l3 ? g.v[7] : g.v[1]);

        const F16v a0 = *reinterpret_cast<const F16v*>(ea + (size_t)eid0 * ED);
        const F16v a1 = *reinterpret_cast<const F16v*>(ea + (size_t)eid1 * ED);
        const F16v a2 = *reinterpret_cast<const F16v*>(ea + (size_t)eid2 * ED);
        const F16v a3 = *reinterpret_cast<const F16v*>(ea + (size_t)eid3 * ED);

        float xv0, xv1, xv2, xv3;
        if (XH) {
            xv0 = __half2float(xh[(size_t)src0 * D + lane]);
            xv1 = __half2float(xh[(size_t)src1 * D + lane]);
            xv2 = __half2float(xh[(size_t)src2 * D + lane]);
            xv3 = __half2float(xh[(size_t)src3 * D + lane]);
        } else {
            xv0 = x[(size_t)src0 * D + lane];
            xv1 = x[(size_t)src1 * D + lane];
            xv2 = x[(size_t)src2 * D + lane];
            xv3 = x[(size_t)src3 * D + lane];
        }

        float d0 = bo, d1 = bo, d2 = bo, d3 = bo;
        #pragma unroll
        for (int k = 0; k < ED; ++k) {
            d0 += a0.f[k] * wv[k];
            d1 += a1.f[k] * wv[k];
            d2 += a2.f[k] * wv[k];
            d3 += a3.f[k] * wv[k];
        }
        iacc += __float2int_rn(fmaxf(d0 + xv0, 0.f) * QSCALE);
        iacc += l1 ? __float2int_rn(fmaxf(d1 + xv1, 0.f) * QSCALE) : 0;
        iacc += l2 ? __float2int_rn(fmaxf(d2 + xv2, 0.f) * QSCALE) : 0;
        iacc += l3 ? __float2int_rn(fmaxf(d3 + xv3, 0.f) * QSCALE) : 0;
    }
    agg[(size_t)n * D + lane] = (float)iacc * (1.0f / QSCALE);
}

// =====================  path B fallback: atomic edge kernel  =================
__global__ __launch_bounds__(256) void edge_kernel(
    const float* __restrict__ x,
    const int*   __restrict__ ei32,
    const float* __restrict__ ea,
    const float* __restrict__ W_edge,
    const float* __restrict__ b_edge,
    float*       __restrict__ agg)
{
    __shared__ float s_ea[64 * ED];
    __shared__ int   s_src[64];
    __shared__ int   s_dst[64];

    const int tid  = threadIdx.x;
    const int lane = tid & 63;
    const int wave = tid >> 6;
    const long long ebase = (long long)blockIdx.x * 64;

    const int hi = ei32[2 * lane + 1];
    const bool is64 = !__any(hi != 0);

    float w[ED];
    #pragma unroll
    for (int i = 0; i < ED / 4; ++i) {
        float4 t = reinterpret_cast<const float4*>(W_edge)[lane * (ED / 4) + i];
        w[4*i+0] = t.x; w[4*i+1] = t.y; w[4*i+2] = t.z; w[4*i+3] = t.w;
    }
    const float bo = b_edge[lane];

    reinterpret_cast<float4*>(s_ea)[tid] =
        reinterpret_cast<const float4*>(ea + ebase * ED)[tid];

    if (tid < 64) {
        long long e = ebase + tid;
        s_src[tid] = is64 ? ei32[2 * e] : ei32[e];
    } else if (tid < 128) {
        long long e = ebase + (tid - 64);
        s_dst[tid - 64] = is64 ? ei32[2 * (NE + e)] : ei32[NE + e];
    }
    __syncthreads();

    #pragma unroll 4
    for (int i = 0; i < 16; ++i) {
        const int el = wave * 16 + i;
        float acc = bo;
        const float* er = s_ea + el * ED;
        #pragma unroll
        for (int k = 0; k < ED; ++k) acc += er[k] * w[k];
        const long long s = s_src[el];
        const long long d = s_dst[el];
        float m = fmaxf(acc + x[s * D + lane], 0.f);
        atomicAdd(&agg[d * D + lane], m);
    }
}

// =====================  node stages  =====================

__global__ __launch_bounds__(256) void node1_kernel(
    const float* __restrict__ x,
    const float* __restrict__ agg,
    const float* __restrict__ W1,
    const float* __restrict__ b1,
    float*       __restrict__ h1,
    float*       __restrict__ colsum,
    float*       __restrict__ colsumsq)
{
    __shared__ float s_h[64 * D];
    const int tid  = threadIdx.x;
    const int o    = tid & 63;
    const int wave = tid >> 6;
    const long long rbase = (long long)blockIdx.x * 64;

    float w[D];
    #pragma unroll
    for (int i = 0; i < D / 4; ++i) {
        float4 t = reinterpret_cast<const float4*>(W1)[o * (D / 4) + i];
        w[4*i+0] = t.x; w[4*i+1] = t.y; w[4*i+2] = t.z; w[4*i+3] = t.w;
    }

    #pragma unroll
    for (int i = 0; i < 4; ++i) {
        const int f4 = tid + 256 * i;
        const long long row = rbase + (f4 >> 4);
        float4 t = make_float4(0.f, 0.f, 0.f, 0.f);
        if (row < NN) {
            float4 a = reinterpret_cast<const float4*>(x)  [row * (D/4) + (f4 & 15)];
            float4 g = reinterpret_cast<const float4*>(agg)[row * (D/4) + (f4 & 15)];
            t.x = a.x + g.x; t.y = a.y + g.y; t.z = a.z + g.z; t.w = a.w + g.w;
        }
        reinterpret_cast<float4*>(s_h)[f4] = t;
    }
    __syncthreads();

    const float bb = b1[o];
    float psum = 0.f, psq = 0.f;
    for (int i = 0; i < 16; ++i) {
        const int r = wave + 4 * i;
        const long long row = rbase + r;
        float acc = bb;
        const float4* sr = reinterpret_cast<const float4*>(s_h + r * D);
        #pragma unroll
        for (int k = 0; k < D / 4; ++k) {
            float4 v = sr[k];
            acc += v.x * w[4*k+0] + v.y * w[4*k+1] + v.z * w[4*k+2] + v.w * w[4*k+3];
        }
        if (row < NN) {
            h1[row * D + o] = acc;
            psum += acc;
            psq  += acc * acc;
        }
    }
    __syncthreads();
    s_h[wave * 64 + o]       = psum;
    s_h[256 + wave * 64 + o] = psq;
    __syncthreads();
    if (tid < 64) {
        float s0 = s_h[tid] + s_h[64 + tid] + s_h[128 + tid] + s_h[192 + tid];
        float q0 = s_h[256 + tid] + s_h[320 + tid] + s_h[384 + tid] + s_h[448 + tid];
        atomicAdd(&colsum[tid], s0);
        atomicAdd(&colsumsq[tid], q0);
    }
}

__global__ void bnstats_kernel(
    const float* __restrict__ colsum,
    const float* __restrict__ colsumsq,
    const float* __restrict__ gamma,
    const float* __restrict__ beta,
    float*       __restrict__ scale,
    float*       __restrict__ shift)
{
    const int o = threadIdx.x;
    const float inv_n = 1.f / (float)NN;
    const float mean = colsum[o] * inv_n;
    const float var  = colsumsq[o] * inv_n - mean * mean;
    const float sc   = gamma[o] * rsqrtf(var + BN_EPS);
    scale[o] = sc;
    shift[o] = beta[o] - mean * sc;
}

__global__ __launch_bounds__(256) void node2_kernel(
    const float* __restrict__ h1,
    const float* __restrict__ scale,
    const float* __restrict__ shift,
    const float* __restrict__ W2,
    const float* __restrict__ b2,
    float*       __restrict__ out)
{
    __shared__ float s_a[64 * D];
    __shared__ float s_sc[D];
    __shared__ float s_sh[D];
    const int tid  = threadIdx.x;
    const int o    = tid & 63;
    const int wave = tid >> 6;
    const long long rbase = (long long)blockIdx.x * 64;

    if (tid < D) { s_sc[tid] = scale[tid]; s_sh[tid] = shift[tid]; }

    float w[D];
    #pragma unroll
    for (int i = 0; i < D / 4; ++i) {
        float4 t = reinterpret_cast<const float4*>(W2)[o * (D / 4) + i];
        w[4*i+0] = t.x; w[4*i+1] = t.y; w[4*i+2] = t.z; w[4*i+3] = t.w;
    }
    __syncthreads();

    #pragma unroll
    for (int i = 0; i < 4; ++i) {
        const int f4 = tid + 256 * i;
        const long long row = rbase + (f4 >> 4);
        float4 t = make_float4(0.f, 0.f, 0.f, 0.f);
        if (row < NN) {
            float4 v = reinterpret_cast<const float4*>(h1)[row * (D/4) + (f4 & 15)];
            const int c = (f4 & 15) * 4;
            t.x = fmaxf(v.x * s_sc[c+0] + s_sh[c+0], 0.f);
            t.y = fmaxf(v.y * s_sc[c+1] + s_sh[c+1], 0.f);
            t.z = fmaxf(v.z * s_sc[c+2] + s_sh[c+2], 0.f);
            t.w = fmaxf(v.w * s_sc[c+3] + s_sh[c+3], 0.f);
        }
        reinterpret_cast<float4*>(s_a)[f4] = t;
    }
    __syncthreads();

    const float bb = b2[o];
    for (int i = 0; i < 16; ++i) {
        const int r = wave + 4 * i;
        const long long row = rbase + r;
        float acc = bb;
        const float4* sr = reinterpret_cast<const float4*>(s_a + r * D);
        #pragma unroll
        for (int k = 0; k < D / 4; ++k) {
            float4 v = sr[k];
            acc += v.x * w[4*k+0] + v.y * w[4*k+1] + v.z * w[4*k+2] + v.w * w[4*k+3];
        }
        if (row < NN) out[row * D + o] = acc;
    }
}

// =====================  launch  =====================

extern "C" void kernel_launch(void* const* d_in, const int* in_sizes, int n_in,
                              void* d_out, int out_size, void* d_ws, size_t ws_size,
                              hipStream_t stream)
{
    const float* x      = (const float*)d_in[0];
    const int*   ei32   = (const int*)  d_in[1];
    const float* ea     = (const float*)d_in[2];
    const float* W_edge = (const float*)d_in[3];
    const float* b_edge = (const float*)d_in[4];
    const float* W1     = (const float*)d_in[5];
    const float* b1     = (const float*)d_in[6];
    const float* gamma  = (const float*)d_in[7];
    const float* beta   = (const float*)d_in[8];
    const float* W2     = (const float*)d_in[9];
    const float* b2     = (const float*)d_in[10];
    float* out = (float*)d_out;

    float*  agg      = (float*)d_ws;                         // NN*D floats
    float*  h1       = agg + (size_t)NN * D;                 // NN*D floats
    int*    cursor   = (int*)(h1 + (size_t)NN * D);          // NN ints
    float*  colsum   = (float*)(cursor + NN);                // 64
    float*  colsumsq = colsum + 64;                          // 64
    float*  scale    = colsumsq + 64;                        // 64
    float*  shift    = scale + 64;                           // 64
    int2*   padded   = (int2*)(shift + 64);                  // NN*CAP int2
    __half* xh       = (__half*)(padded + (size_t)NN * CAP); // NN*D halves
    int*    gcur     = (int*)(xh + (size_t)NN * D);          // NBKT ints
    uint2*  bucketed = (uint2*)h1;                           // aliases h1 (dead until node1)

    const size_t need_base = (size_t)(2 * NN * D + NN + 256) * 4 + (size_t)NN * CAP * 8;
    const size_t need_xh   = need_base + (size_t)NN * D * 2;
    const size_t need_rx   = need_xh + (size_t)NBKT * 4;

    if (ws_size >= need_rx) {
        // radix-partition path: no 1M global atomics, no random-line stores
        hipMemsetAsync(gcur, 0, (size_t)NBKT * 4, stream);
        hipMemsetAsync(colsum, 0, 256 * 4, stream);   // BN accumulators: MUST zero every call
        xhalf_kernel<<<(NN * D / 4 + 255) / 256, 256, 0, stream>>>(x, xh);
        partA_kernel<<<(NE + EPB - 1) / EPB, 256, 0, stream>>>(ei32, gcur, bucketed);
        partB_kernel<<<NBKT, 512, 0, stream>>>(bucketed, gcur, cursor, padded);
        gather_kernel<true><<<NN / 8, 256, 0, stream>>>(padded, cursor, x, xh, ea, W_edge, b_edge, agg, 0, NN / 2);
        gather_kernel<true><<<NN / 8, 256, 0, stream>>>(padded, cursor, x, xh, ea, W_edge, b_edge, agg, NN / 2, NN);
    } else if (ws_size >= need_base) {
        hipMemsetAsync(cursor, 0, (size_t)(NN + 256) * 4, stream);
        scatter_kernel<<<(NE + 255) / 256, 256, 0, stream>>>(ei32, cursor, padded);
        gather_kernel<false><<<NN / 8, 256, 0, stream>>>(padded, cursor, x, xh, ea, W_edge, b_edge, agg, 0, NN / 2);
        gather_kernel<false><<<NN / 8, 256, 0, stream>>>(padded, cursor, x, xh, ea, W_edge, b_edge, agg, NN / 2, NN);
    } else {
        hipMemsetAsync(agg, 0, (size_t)NN * D * 4, stream);
        hipMemsetAsync(cursor, 0, (size_t)(NN + 256) * 4, stream);
        edge_kernel<<<NE / 64, 256, 0, stream>>>(x, ei32, ea, W_edge, b_edge, agg);
    }
    node1_kernel<<<(NN + 63) / 64, 256, 0, stream>>>(x, agg, W1, b1, h1, colsum, colsumsq);
    bnstats_kernel<<<1, 64, 0, stream>>>(colsum, colsumsq, gamma, beta, scale, shift);
    node2_kernel<<<(NN + 63) / 64, 256, 0, stream>>>(h1, scale, shift, W2, b2, out);
}